// Round 1
// baseline (1198.697 us; speedup 1.0000x reference)
//
#include <hip/hip_runtime.h>
#include <cmath>
#include <cstdint>

// B=16, S=256, H=768, L=37, Y=2S=512.
// d_out = [loss(1)] [rel_preds 16*256*512*37] [arc_preds 16*256*512]  (fp32)
//
// Pipeline (bf16 MFMA, fp32 accum). Ones-column is factored out of all
// contractions (K=768 exactly) and applied as fp32 epilogue biases:
//   yrb   = [hidden;deps]          bf16 [16][512][768]   (deps rows double as "xa")
//   A1    = deps @ W_arc[:768] + W_arc[768,:]            (bias in epilogue)
//   arc   = A1 @ heads^T
//   bias2 = deps @ W_rel[o,:768,768] + W_rel[o,768,768]
//   M     = deps @ W_rel[o,:768,:768]^T + W_rel[o,768,:]  [4096][oc][768] bf16
//   rel   = M . yrb + bias2        (LDS-restaged coalesced epilogue)
//   loss  = masked mean of log-softmax picks
//
// Big GEMMs (M, rel) use RT=2: 256x128 block tile, 4 waves, 128x64 wave tile
// -> 43.7 FLOP per LDS byte read (was 32), 2x MFMA per barrier interval.

#define NB 16
#define SS 256
#define HH 768
#define LLn 37
#define YY 512

static const long long REL_ELEMS = (long long)NB * SS * YY * LLn;

typedef __bf16 bf16_t;
typedef __bf16 bf16x8 __attribute__((ext_vector_type(8)));
typedef float f32x4 __attribute__((ext_vector_type(4)));

__device__ __forceinline__ void async_copy16(const void* g, void* l) {
  __builtin_amdgcn_global_load_lds((__attribute__((address_space(1))) void*)(g),
                                   (__attribute__((address_space(3))) void*)(l),
                                   16, 0, 0);
}

// ---------------- prep kernels ----------------

__global__ void hid_rows(const float* __restrict__ hidden, bf16_t* __restrict__ yrb) {
  const long long r = blockIdx.x;            // b*256+y
  const int b = (int)(r >> 8), y = (int)(r & 255);
  const float* src = hidden + r * HH;
  bf16_t* dst = yrb + ((long long)b * YY + y) * HH;
  for (int h = threadIdx.x; h < HH; h += 256) dst[h] = (bf16_t)src[h];
}

// deps row x of batch b -> yrb[b][256+x][:768].  valid iff word_starts[x+1]!=0
// (starts are strictly increasing positive, zero-padded).
__global__ void build_deps2(const float* __restrict__ hidden,
                            const int* __restrict__ word_starts,
                            bf16_t* __restrict__ yrb) {
  const int x = blockIdx.x, b = blockIdx.y, t = threadIdx.x;
  const int ws0 = word_starts[b * SS + x];
  const int ws1 = (x + 1 < SS) ? word_starts[b * SS + x + 1] : 0;
  const bool valid = (x + 1 < SS) && (ws1 != 0);
  const int start = min(max(ws0, 0), SS);
  const int end = min(max(ws1, 0), SS);
  const int len = max(end - start, 1);
  const float inv = 1.0f / (float)len;
  const float* hb = hidden + (long long)b * SS * HH;
  bf16_t* yr = yrb + ((long long)b * YY + SS + x) * HH;
  for (int h = t; h < HH; h += 256) {
    float s = 0.f;
    if (valid) for (int tt = start; tt < end; ++tt) s += hb[(long long)tt * HH + h];
    yr[h] = (bf16_t)(valid ? s * inv : 0.f);
  }
}

// W_arc [769,768] fp32 -> Wab [768][768] bf16 transposed (rows i<768 only)
__global__ void conv_warc(const float* __restrict__ W, bf16_t* __restrict__ Wab) {
  __shared__ float tbuf[32][33];
  const int i0 = blockIdx.x * 32, j0 = blockIdx.y * 32;
  const int tx = threadIdx.x, ty = threadIdx.y;   // 32x8
  for (int rr = 0; rr < 32; rr += 8)
    tbuf[ty + rr][tx] = W[(long long)(i0 + ty + rr) * HH + j0 + tx];
  __syncthreads();
  for (int rr = 0; rr < 32; rr += 8)
    Wab[(long long)(j0 + ty + rr) * HH + i0 + tx] = (bf16_t)tbuf[tx][ty + rr];
}

// W_rel [o][769][769] fp32 -> Wbc [z][768][768] bf16 transposed (i,j<768)
__global__ void conv_wrel(const float* __restrict__ W, bf16_t* __restrict__ Wb, int o0) {
  __shared__ float tbuf[32][33];
  const int o = o0 + blockIdx.z;
  const int i0 = blockIdx.x * 32, j0 = blockIdx.y * 32;
  const int tx = threadIdx.x, ty = threadIdx.y;   // 32x8
  const float* Wo = W + (long long)o * (HH + 1) * (HH + 1);
  for (int rr = 0; rr < 32; rr += 8)
    tbuf[ty + rr][tx] = Wo[(long long)(i0 + ty + rr) * (HH + 1) + j0 + tx];
  __syncthreads();
  bf16_t* Wbo = Wb + (long long)blockIdx.z * HH * HH;
  for (int rr = 0; rr < 32; rr += 8)
    Wbo[(long long)(j0 + ty + rr) * HH + i0 + tx] = (bf16_t)tbuf[tx][ty + rr];
}

// biases + the j=768 weight column, one kernel:
//  WbiasJ[o][j] = W_rel[o][768][j]        (fp32, per-col bias of M)
//  Wb768[o][i]  = W_rel[o][i][768]        (bf16, B-matrix of bias2 GEMM; o>=37 -> 0)
//  bias768b[o]  = W_rel[o][768][768]      (fp32)
//  biasArc[j]   = W_arc[768][j]           (fp32)
//  lossacc[0..1] = 0
__global__ void build_misc(const float* __restrict__ W_rel, const float* __restrict__ W_arc,
                           float* __restrict__ WbiasJ, bf16_t* __restrict__ Wb768,
                           float* __restrict__ bias768b, float* __restrict__ biasArc,
                           float* __restrict__ lossacc) {
  const int blk = blockIdx.x, t = threadIdx.x;
  if (blk < LLn) {
    const int o = blk;
    const float* Wo = W_rel + (long long)o * (HH + 1) * (HH + 1);
    for (int j = t; j < HH; j += 256)
      WbiasJ[(long long)o * HH + j] = Wo[(long long)HH * (HH + 1) + j];
    for (int i = t; i < HH; i += 256)
      Wb768[(long long)o * HH + i] = (bf16_t)Wo[(long long)i * (HH + 1) + HH];
    if (t == 0) bias768b[o] = Wo[(long long)HH * (HH + 1) + HH];
  } else if (blk == LLn) {
    for (int j = t; j < HH; j += 256) biasArc[j] = W_arc[(long long)HH * HH + j];
    if (t == 0) { lossacc[0] = 0.f; lossacc[1] = 0.f; }
  } else {
    for (int i = t; i < (128 - LLn) * HH; i += 256) Wb768[(long long)LLn * HH + i] = (bf16_t)0.f;
    if (t + LLn < 128) bias768b[t + LLn] = 0.f;
  }
}

// ---------------- GEMM: C = A * B^T, (RT*128)x128 tile, bf16 MFMA 16x16x32 ----
// RT=1: 128x128 tile, 64x64 wave tile (4 waves).  RT=2: 256x128, 128x64 wave tile.
// aview!=0: A rows r=b*256+x map to yrb[b][256+x][:] (deps view), lda = row stride.
// cbias (optional): per-column fp32 bias, indexed cbias[z*sbias + col].
// MODE 0: bf16 out at Cb + z*sCz + row*ldc + col   (+cbias)
// MODE 1: fp32 out at Cf + z*sCz + row*ldc + col   (+cbias)
// MODE 2: rel out; col n -> (x=n/OC, o=o0+n%OC); LDS-restaged coalesced + bias_xo

template<int RT, int MODE>
__global__ __launch_bounds__(256)
void gemm_bt(const bf16_t* __restrict__ A, long long sAz, int lda, int aview,
             const bf16_t* __restrict__ B, long long sBz, int ldb,
             int K,
             float* __restrict__ Cf, bf16_t* __restrict__ Cb,
             long long sCz, int ldc,
             const float* __restrict__ cbias, int sbias,
             int OC, int o0, const float* __restrict__ bias_xo) {
  constexpr int SM0 = RT * 8192 + 8192;
  constexpr int SMEM = SM0 > 16896 ? SM0 : 16896;   // epilogue ebuf 32x132 f32
  __shared__ __align__(16) char smem_raw[SMEM];
  bf16_t* As = (bf16_t*)smem_raw;                    // [RT*128][32]
  bf16_t* Bs = (bf16_t*)(smem_raw + RT * 8192);      // [128][32]
  const int tid = threadIdx.x;
  const int w = tid >> 6;
  const int lane = tid & 63;
  const int z = blockIdx.z;
  const long long row0 = (long long)blockIdx.y * (RT * 128);
  const long long col0 = (long long)blockIdx.x * 128;
  const bf16_t* Ab;
  if (aview) {
    const long long bb = row0 >> 8;                  // tile lies within one b
    Ab = A + (bb * 512 + 256 + (row0 & 255)) * (long long)lda;
  } else {
    Ab = A + z * sAz + row0 * lda;
  }
  const bf16_t* Bb = B + z * sBz + col0 * ldb;

  const int r_in = lane >> 2;
  const int kofs = (lane & 3) * 8;
  const bf16_t* gA[2 * RT];
  bf16_t* lA[2 * RT];
  #pragma unroll
  for (int c = 0; c < 2 * RT; c++) {
    gA[c] = Ab + (long long)(w * (32 * RT) + c * 16 + r_in) * lda + kofs;
    lA[c] = &As[(w * (32 * RT) + c * 16) * 32];
  }
  const bf16_t* gB0 = Bb + (long long)(w * 32 + r_in) * ldb + kofs;
  const bf16_t* gB1 = gB0 + 16ll * ldb;
  bf16_t* lB0 = &Bs[(w * 32) * 32];
  bf16_t* lB1 = &Bs[(w * 32 + 16) * 32];

  f32x4 acc[4 * RT][4];
  #pragma unroll
  for (int i = 0; i < 4 * RT; i++)
    #pragma unroll
    for (int j = 0; j < 4; j++)
      #pragma unroll
      for (int e = 0; e < 4; e++) acc[i][j][e] = 0.f;

  const int wm = (w >> 1) * (64 * RT), wn = (w & 1) * 64;
  const int fr = lane & 15;
  const int fq = lane >> 4;
  const int aoff = fq * 8;

  for (int k0 = 0; k0 < K; k0 += 32) {
    #pragma unroll
    for (int c = 0; c < 2 * RT; c++) async_copy16(gA[c] + k0, lA[c]);
    async_copy16(gB0 + k0, lB0);
    async_copy16(gB1 + k0, lB1);
    __syncthreads();
    bf16x8 bfr[4];
    #pragma unroll
    for (int t = 0; t < 4; t++) bfr[t] = *(const bf16x8*)&Bs[(wn + t * 16 + fr) * 32 + aoff];
    #pragma unroll
    for (int tm = 0; tm < 4 * RT; tm++) {
      const bf16x8 af = *(const bf16x8*)&As[(wm + tm * 16 + fr) * 32 + aoff];
      #pragma unroll
      for (int tn = 0; tn < 4; tn++)
        acc[tm][tn] = __builtin_amdgcn_mfma_f32_16x16x32_bf16(af, bfr[tn], acc[tm][tn], 0, 0, 0);
    }
    __syncthreads();
  }

  if (MODE == 2) {
    // restage through LDS; write coalesced runs of <=OC consecutive floats
    float* ebuf = (float*)smem_raw;          // [32][132]
    const int c = tid & 127;
    const int rgrp = tid >> 7;               // 0..1
    const int n = (int)col0 + c;
    const int x = n / OC;
    const int o = o0 + (n - x * OC);
    const float bias = bias_xo[(((long long)z << 8) + x) * 128 + o];
    float* outp = Cf + z * sCz + (long long)x * (YY * LLn) + o;
    #pragma unroll
    for (int ch = 0; ch < 4 * RT; ch++) {
      #pragma unroll
      for (int tn = 0; tn < 4; tn++)
        #pragma unroll
        for (int e = 0; e < 4; e++)
          ebuf[((w >> 1) * 16 + fq * 4 + e) * 132 + wn + tn * 16 + fr] = acc[ch][tn][e];
      __syncthreads();
      const long long ybase = row0 + (long long)rgrp * (64 * RT) + ch * 16;
      #pragma unroll
      for (int r = 0; r < 16; r++)
        outp[(ybase + r) * LLn] = ebuf[(rgrp * 16 + r) * 132 + c] + bias;
      __syncthreads();
    }
  } else {
    const int er = fq * 4;
    #pragma unroll
    for (int tn = 0; tn < 4; tn++) {
      const long long col = col0 + wn + tn * 16 + fr;
      const float bv = cbias ? cbias[(long long)z * sbias + col] : 0.f;
      #pragma unroll
      for (int tm = 0; tm < 4 * RT; tm++) {
        const int rl = wm + tm * 16 + er;
        if (MODE == 0) {
          bf16_t* dst = Cb + z * sCz + col;
          #pragma unroll
          for (int r = 0; r < 4; r++)
            dst[(row0 + rl + r) * (long long)ldc] = (bf16_t)(acc[tm][tn][r] + bv);
        } else {
          float* dst = Cf + z * sCz + col;
          #pragma unroll
          for (int r = 0; r < 4; r++)
            dst[(row0 + rl + r) * (long long)ldc] = acc[tm][tn][r] + bv;
        }
      }
    }
  }
}

// ---------------- loss ----------------

__device__ __forceinline__ float wave_max(float v) {
  #pragma unroll
  for (int off = 32; off > 0; off >>= 1) v = fmaxf(v, __shfl_xor(v, off));
  return v;
}
__device__ __forceinline__ float wave_sum(float v) {
  #pragma unroll
  for (int off = 32; off > 0; off >>= 1) v += __shfl_xor(v, off);
  return v;
}

__global__ void loss_kernel(const float* __restrict__ arc, const float* __restrict__ rel,
                            const int* __restrict__ la, const int* __restrict__ lr,
                            float* __restrict__ acc) {
  const int r = blockIdx.x;
  const int lane = threadIdx.x;    // 64
  const int lab = la[r];
  const float* ar = arc + (long long)r * YY;
  float v[8]; float m = -INFINITY;
  #pragma unroll
  for (int i = 0; i < 8; i++) { v[i] = ar[lane + 64 * i]; m = fmaxf(m, v[i]); }
  m = wave_max(m);
  float s = 0.f;
  #pragma unroll
  for (int i = 0; i < 8; i++) s += expf(v[i] - m);
  s = wave_sum(s);
  const float lse_a = m + logf(s);
  const int safe = lab < 0 ? 0 : (lab > YY - 1 ? YY - 1 : lab);
  const float* rr = rel + ((long long)r * YY + safe) * LLn;
  const float rv = (lane < LLn) ? rr[lane] : -INFINITY;
  const float m2 = wave_max(rv);
  const float s2 = wave_sum((lane < LLn) ? expf(rv - m2) : 0.f);
  const float lse_r = m2 + logf(s2);
  if (lane == 0 && lab != 0) {
    const float ll = (ar[safe] - lse_a) + (rr[lr[r]] - lse_r);
    atomicAdd(&acc[0], ll);
    atomicAdd(&acc[1], 1.f);
  }
}

__global__ void finalize(const float* __restrict__ acc, float* __restrict__ out) {
  out[0] = -acc[0] / acc[1];
}

// ---------------- launch ----------------

extern "C" void kernel_launch(void* const* d_in, const int* in_sizes, int n_in,
                              void* d_out, int out_size, void* d_ws, size_t ws_size,
                              hipStream_t stream) {
  (void)in_sizes; (void)n_in; (void)out_size;
  const float* hidden      = (const float*)d_in[0];
  const float* W_arc       = (const float*)d_in[1];
  const float* W_rel       = (const float*)d_in[2];
  const int* word_starts   = (const int*)d_in[3];
  const int* labels_arcs   = (const int*)d_in[4];
  const int* labels_rels   = (const int*)d_in[5];

  float* out = (float*)d_out;
  float* rel_out = out + 1;
  float* arc_out = rel_out + REL_ELEMS;

  char* ws = (char*)d_ws;
  float* lossacc  = (float*)ws;                                 // 2 floats (256B slot)
  bf16_t* yrb     = (bf16_t*)(ws + 256);                        // [16][512][768]
  bf16_t* Wab     = yrb + (size_t)NB * YY * HH;                 // [768][768]
  bf16_t* A1      = Wab + (size_t)HH * HH;                      // [4096][768]
  bf16_t* Wb768   = A1 + (size_t)NB * SS * HH;                  // [128][768]
  float*  biasArc = (float*)(Wb768 + (size_t)128 * HH);         // [768]
  float*  bias768b= biasArc + HH;                               // [128]
  float*  d_bias2 = bias768b + 128;                             // [4096][128] fp32
  float*  WbiasJ  = d_bias2 + (size_t)NB * SS * 128;            // [37][768] fp32
  bf16_t* Wbc     = (bf16_t*)(WbiasJ + (size_t)LLn * HH);       // [OC][768][768]

  const size_t fixedB = 256 +
      2 * ((size_t)NB * YY * HH + (size_t)HH * HH + (size_t)NB * SS * HH +
           (size_t)128 * HH) +
      4 * ((size_t)HH + 128 + (size_t)NB * SS * 128 + (size_t)LLn * HH);
  const size_t perOC = 2 * ((size_t)HH * HH + (size_t)NB * SS * HH);
  int OC = 1;
  if (ws_size > fixedB + perOC) {
    const size_t m = (ws_size - fixedB) / perOC;
    OC = (m > (size_t)LLn) ? LLn : (int)m;
  }
  bf16_t* M_p = Wbc + (size_t)OC * HH * HH;                     // [4096][OC][768]

  hid_rows<<<NB * SS, 256, 0, stream>>>(hidden, yrb);
  build_deps2<<<dim3(SS, NB), 256, 0, stream>>>(hidden, word_starts, yrb);
  conv_warc<<<dim3(24, 24), dim3(32, 8), 0, stream>>>(W_arc, Wab);
  build_misc<<<39, 256, 0, stream>>>(W_rel, W_arc, WbiasJ, Wb768, bias768b, biasArc, lossacc);

  // A1 = deps @ W_arc[:768] + biasArc : [4096 x 768], K=768
  gemm_bt<1, 0><<<dim3(6, 32, 1), 256, 0, stream>>>(
      yrb, 0, HH, 1, Wab, 0, HH, HH,
      nullptr, A1, 0, HH, biasArc, 0, 0, 0, nullptr);
  // arc_preds = A1 . heads^T, K=768
  gemm_bt<1, 1><<<dim3(4, 2, NB), 256, 0, stream>>>(
      A1, (long long)SS * HH, HH, 0,
      yrb, (long long)YY * HH, HH, HH,
      arc_out, nullptr, (long long)SS * YY, YY, nullptr, 0, 0, 0, nullptr);
  // bias2 = deps @ Wb768^T + bias768b : [4096 x 128], K=768
  gemm_bt<1, 1><<<dim3(1, 32, 1), 256, 0, stream>>>(
      yrb, 0, HH, 1, Wb768, 0, HH, HH,
      d_bias2, nullptr, 0, 128, bias768b, 0, 0, 0, nullptr);

  for (int o0 = 0; o0 < LLn; o0 += OC) {
    const int oc = (LLn - o0 < OC) ? (LLn - o0) : OC;
    conv_wrel<<<dim3(24, 24, oc), dim3(32, 8), 0, stream>>>(W_rel, Wbc, o0);
    // M[b,x,o,j<768] = deps . Wbc[o]^T + WbiasJ[o], K=768  (256x128 tiles)
    gemm_bt<2, 0><<<dim3(6, 16, oc), 256, 0, stream>>>(
        yrb, 0, HH, 1,
        Wbc, (long long)HH * HH, HH, HH,
        nullptr, M_p, HH, oc * HH, WbiasJ + (long long)o0 * HH, HH, 0, 0, nullptr);
    // rel[b,x,y,o] = yrb[b,y,:] . M[b,x,o,:] + bias2[b,x,o], K=768  (256x128 tiles)
    gemm_bt<2, 2><<<dim3(2 * oc, 2, NB), 256, 0, stream>>>(
        yrb, (long long)YY * HH, HH, 0,
        M_p, (long long)SS * oc * HH, HH, HH,
        rel_out, nullptr, (long long)SS * YY * LLn, 0, nullptr, 0,
        oc, o0, d_bias2);
  }

  loss_kernel<<<NB * SS, 64, 0, stream>>>(arc_out, rel_out, labels_arcs, labels_rels, lossacc);
  finalize<<<1, 1, 0, stream>>>(lossacc, out);
}

// Round 2
// 998.916 us; speedup vs baseline: 1.2000x; 1.2000x over previous
//
#include <hip/hip_runtime.h>
#include <cmath>
#include <cstdint>

// B=16, S=256, H=768, L=37, Y=2S=512.
// d_out = [loss(1)] [rel_preds 16*256*512*37] [arc_preds 16*256*512]  (fp32)
//
// Pipeline (bf16 MFMA, fp32 accum). Ones-column factored out of all
// contractions (K=768 exactly), applied as fp32 epilogue biases:
//   yrb   = [hidden;deps]          bf16 [16][512][768]  (deps rows double as "xa")
//   A1    = deps @ W_arc[:768] + W_arc[768,:]
//   arc   = A1 @ heads^T
//   bias2 = deps . W_rel[o,:768,768] + W_rel[o,768,768]   (wave-dot kernel)
//   M     = deps @ W_rel[o,:768,:768]^T + W_rel[o,768,:]  [4096][oc][768] bf16
//   rel   = M . yrb + bias2        (LDS-restaged coalesced epilogue)
//
// GEMM: 128x128 tile, 4 waves (64x64/wave, 68 VGPR -> ~2.5 blocks/CU), with
// single-barrier double-buffered LDS: stage tile t+1 || compute tile t, one
// __syncthreads per K-step (24 barriers instead of 48; stage latency hidden
// under ds_read+MFMA).

#define NB 16
#define SS 256
#define HH 768
#define LLn 37
#define YY 512

static const long long REL_ELEMS = (long long)NB * SS * YY * LLn;

typedef __bf16 bf16_t;
typedef __bf16 bf16x8 __attribute__((ext_vector_type(8)));
typedef float f32x4 __attribute__((ext_vector_type(4)));

__device__ __forceinline__ void async_copy16(const void* g, void* l) {
  __builtin_amdgcn_global_load_lds((__attribute__((address_space(1))) void*)(g),
                                   (__attribute__((address_space(3))) void*)(l),
                                   16, 0, 0);
}

__device__ __forceinline__ float wave_max(float v) {
  #pragma unroll
  for (int off = 32; off > 0; off >>= 1) v = fmaxf(v, __shfl_xor(v, off));
  return v;
}
__device__ __forceinline__ float wave_sum(float v) {
  #pragma unroll
  for (int off = 32; off > 0; off >>= 1) v += __shfl_xor(v, off);
  return v;
}

// ---------------- prep kernels ----------------

__global__ void hid_rows(const float* __restrict__ hidden, bf16_t* __restrict__ yrb) {
  const long long r = blockIdx.x;            // b*256+y
  const int b = (int)(r >> 8), y = (int)(r & 255);
  const float4* src = (const float4*)(hidden + r * HH);
  bf16_t* dst = yrb + ((long long)b * YY + y) * HH;
  const int t = threadIdx.x;                 // 192 threads: 192*4 = 768
  const float4 v = src[t];
  bf16_t o4[4] = {(bf16_t)v.x, (bf16_t)v.y, (bf16_t)v.z, (bf16_t)v.w};
  *(ushort4*)(dst + t * 4) = *(ushort4*)o4;
}

// deps row x of batch b -> yrb[b][256+x][:768].  valid iff word_starts[x+1]!=0
__global__ void build_deps2(const float* __restrict__ hidden,
                            const int* __restrict__ word_starts,
                            bf16_t* __restrict__ yrb) {
  const int x = blockIdx.x, b = blockIdx.y, t = threadIdx.x;
  const int ws0 = word_starts[b * SS + x];
  const int ws1 = (x + 1 < SS) ? word_starts[b * SS + x + 1] : 0;
  const bool valid = (x + 1 < SS) && (ws1 != 0);
  const int start = min(max(ws0, 0), SS);
  const int end = min(max(ws1, 0), SS);
  const int len = max(end - start, 1);
  const float inv = 1.0f / (float)len;
  const float* hb = hidden + (long long)b * SS * HH;
  bf16_t* yr = yrb + ((long long)b * YY + SS + x) * HH;
  for (int h = t; h < HH; h += 256) {
    float s = 0.f;
    if (valid) for (int tt = start; tt < end; ++tt) s += hb[(long long)tt * HH + h];
    yr[h] = (bf16_t)(valid ? s * inv : 0.f);
  }
}

// W_arc [769,768] fp32 -> Wab [768][768] bf16 transposed (rows i<768 only)
__global__ void conv_warc(const float* __restrict__ W, bf16_t* __restrict__ Wab) {
  __shared__ float tbuf[32][33];
  const int i0 = blockIdx.x * 32, j0 = blockIdx.y * 32;
  const int tx = threadIdx.x, ty = threadIdx.y;   // 32x8
  for (int rr = 0; rr < 32; rr += 8)
    tbuf[ty + rr][tx] = W[(long long)(i0 + ty + rr) * HH + j0 + tx];
  __syncthreads();
  for (int rr = 0; rr < 32; rr += 8)
    Wab[(long long)(j0 + ty + rr) * HH + i0 + tx] = (bf16_t)tbuf[tx][ty + rr];
}

// W_rel [o][769][769] fp32 -> Wbc [z][768][768] bf16 transposed (i,j<768)
__global__ void conv_wrel(const float* __restrict__ W, bf16_t* __restrict__ Wb, int o0) {
  __shared__ float tbuf[32][33];
  const int o = o0 + blockIdx.z;
  const int i0 = blockIdx.x * 32, j0 = blockIdx.y * 32;
  const int tx = threadIdx.x, ty = threadIdx.y;   // 32x8
  const float* Wo = W + (long long)o * (HH + 1) * (HH + 1);
  for (int rr = 0; rr < 32; rr += 8)
    tbuf[ty + rr][tx] = Wo[(long long)(i0 + ty + rr) * (HH + 1) + j0 + tx];
  __syncthreads();
  bf16_t* Wbo = Wb + (long long)blockIdx.z * HH * HH;
  for (int rr = 0; rr < 32; rr += 8)
    Wbo[(long long)(j0 + ty + rr) * HH + i0 + tx] = (bf16_t)tbuf[tx][ty + rr];
}

// biases + the j=768 weight column:
//  WbiasJ[o][j] = W_rel[o][768][j]   (fp32, per-col bias of M)
//  Wb768[o][i]  = W_rel[o][i][768]   (bf16, weights of bias2 dot)
//  bias768b[o]  = W_rel[o][768][768] (fp32)
//  biasArc[j]   = W_arc[768][j]      (fp32);  lossacc zeroed
__global__ void build_misc(const float* __restrict__ W_rel, const float* __restrict__ W_arc,
                           float* __restrict__ WbiasJ, bf16_t* __restrict__ Wb768,
                           float* __restrict__ bias768b, float* __restrict__ biasArc,
                           float* __restrict__ lossacc) {
  const int blk = blockIdx.x, t = threadIdx.x;
  if (blk < LLn) {
    const int o = blk;
    const float* Wo = W_rel + (long long)o * (HH + 1) * (HH + 1);
    for (int j = t; j < HH; j += 256)
      WbiasJ[(long long)o * HH + j] = Wo[(long long)HH * (HH + 1) + j];
    for (int i = t; i < HH; i += 256)
      Wb768[(long long)o * HH + i] = (bf16_t)Wo[(long long)i * (HH + 1) + HH];
    if (t == 0) bias768b[o] = Wo[(long long)HH * (HH + 1) + HH];
  } else {
    for (int j = t; j < HH; j += 256) biasArc[j] = W_arc[(long long)HH * HH + j];
    if (t == 0) { lossacc[0] = 0.f; lossacc[1] = 0.f; }
  }
}

// bias2[r][o] = deps[r] . Wb768[o] + bias768b[o]   (r = b*256+x, o<37)
// 4096 blocks x 256 threads; wave w handles o = w, w+4, ...
__global__ void bias2_kernel(const bf16_t* __restrict__ yrb,
                             const bf16_t* __restrict__ Wb768,
                             const float* __restrict__ bias768b,
                             float* __restrict__ d_bias2) {
  const int r = blockIdx.x;
  const int b = r >> 8, x = r & 255;
  const bf16_t* dep = yrb + ((long long)b * YY + SS + x) * HH;
  const int w = threadIdx.x >> 6, lane = threadIdx.x & 63;
  __shared__ float drow[HH];
  for (int h = threadIdx.x; h < HH; h += 256) drow[h] = (float)dep[h];
  __syncthreads();
  for (int o = w; o < LLn; o += 4) {
    const bf16_t* wrow = Wb768 + (long long)o * HH;
    float s = 0.f;
    #pragma unroll
    for (int i = 0; i < HH / 64; i++) s += drow[lane + 64 * i] * (float)wrow[lane + 64 * i];
    s = wave_sum(s);
    if (lane == 0) d_bias2[(long long)r * 128 + o] = s + bias768b[o];
  }
}

// ---------------- GEMM: C = A * B^T, 128x128 tile, bf16 MFMA 16x16x32 -------
// Single-barrier double-buffered LDS (stage t+1 || compute t).
// aview!=0: A rows r=b*256+x map to yrb[b][256+x][:] (deps view).
// cbias (optional): per-column fp32 bias, cbias[z*sbias + col].
// MODE 0: bf16 out at Cb + z*sCz + row*ldc + col   (+cbias)
// MODE 1: fp32 out at Cf + z*sCz + row*ldc + col   (+cbias)
// MODE 2: rel out; col n -> (x=n/OC, o=o0+n%OC); LDS-restaged coalesced + bias_xo

template<int MODE>
__global__ __launch_bounds__(256)
void gemm_bt(const bf16_t* __restrict__ A, long long sAz, int lda, int aview,
             const bf16_t* __restrict__ B, long long sBz, int ldb,
             int K,
             float* __restrict__ Cf, bf16_t* __restrict__ Cb,
             long long sCz, int ldc,
             const float* __restrict__ cbias, int sbias,
             int OC, int o0, const float* __restrict__ bias_xo) {
  __shared__ __align__(16) char smem_raw[32768];   // 2 bufs x (A 8KB + B 8KB); ebuf 16896 fits
  bf16_t* const lds = (bf16_t*)smem_raw;           // buf c at c*8192 elems; B at +4096
  const int tid = threadIdx.x;
  const int w = tid >> 6;
  const int lane = tid & 63;
  const int z = blockIdx.z;
  const long long row0 = (long long)blockIdx.y * 128;
  const long long col0 = (long long)blockIdx.x * 128;
  const bf16_t* Ab;
  if (aview) {
    const long long bb = row0 >> 8;                // tile lies within one b
    Ab = A + (bb * 512 + 256 + (row0 & 255)) * (long long)lda;
  } else {
    Ab = A + z * sAz + row0 * lda;
  }
  const bf16_t* Bb = B + z * sBz + col0 * ldb;

  const int r_in = lane >> 2;
  const int kofs = (lane & 3) * 8;
  const bf16_t* gA0 = Ab + (long long)(w * 32 + r_in) * lda + kofs;
  const bf16_t* gA1 = gA0 + 16ll * lda;
  const bf16_t* gB0 = Bb + (long long)(w * 32 + r_in) * ldb + kofs;
  const bf16_t* gB1 = gB0 + 16ll * ldb;
  const int lA0 = (w * 32) * 32;
  const int lA1 = (w * 32 + 16) * 32;
  const int lB0 = 4096 + (w * 32) * 32;
  const int lB1 = 4096 + (w * 32 + 16) * 32;

  f32x4 acc[4][4];
  #pragma unroll
  for (int i = 0; i < 4; i++)
    #pragma unroll
    for (int j = 0; j < 4; j++)
      #pragma unroll
      for (int e = 0; e < 4; e++) acc[i][j][e] = 0.f;

  const int wm = (w >> 1) * 64, wn = (w & 1) * 64;
  const int fr = lane & 15;
  const int fq = lane >> 4;
  const int aoff = fq * 8;

  // prologue: stage tile 0 into buf 0
  async_copy16(gA0, lds + lA0);
  async_copy16(gA1, lds + lA1);
  async_copy16(gB0, lds + lB0);
  async_copy16(gB1, lds + lB1);
  __syncthreads();

  int cur = 0;
  for (int k0 = 32; k0 < K; k0 += 32) {
    bf16_t* nb = lds + (cur ^ 1) * 8192;
    async_copy16(gA0 + k0, nb + lA0);
    async_copy16(gA1 + k0, nb + lA1);
    async_copy16(gB0 + k0, nb + lB0);
    async_copy16(gB1 + k0, nb + lB1);
    const bf16_t* cb = lds + cur * 8192;
    bf16x8 af[4], bfr[4];
    #pragma unroll
    for (int t = 0; t < 4; t++) af[t]  = *(const bf16x8*)&cb[(wm + t * 16 + fr) * 32 + aoff];
    #pragma unroll
    for (int t = 0; t < 4; t++) bfr[t] = *(const bf16x8*)&cb[4096 + (wn + t * 16 + fr) * 32 + aoff];
    #pragma unroll
    for (int tm = 0; tm < 4; tm++)
      #pragma unroll
      for (int tn = 0; tn < 4; tn++)
        acc[tm][tn] = __builtin_amdgcn_mfma_f32_16x16x32_bf16(af[tm], bfr[tn], acc[tm][tn], 0, 0, 0);
    __syncthreads();   // drains stage (vmcnt 0) + all waves done with buf cur
    cur ^= 1;
  }
  {  // last tile (no prefetch)
    const bf16_t* cb = lds + cur * 8192;
    bf16x8 af[4], bfr[4];
    #pragma unroll
    for (int t = 0; t < 4; t++) af[t]  = *(const bf16x8*)&cb[(wm + t * 16 + fr) * 32 + aoff];
    #pragma unroll
    for (int t = 0; t < 4; t++) bfr[t] = *(const bf16x8*)&cb[4096 + (wn + t * 16 + fr) * 32 + aoff];
    #pragma unroll
    for (int tm = 0; tm < 4; tm++)
      #pragma unroll
      for (int tn = 0; tn < 4; tn++)
        acc[tm][tn] = __builtin_amdgcn_mfma_f32_16x16x32_bf16(af[tm], bfr[tn], acc[tm][tn], 0, 0, 0);
  }

  if (MODE == 2) {
    __syncthreads();                         // smem reuse: all reads done
    float* ebuf = (float*)smem_raw;          // [32][132]
    const int c = tid & 127;
    const int rgrp = tid >> 7;               // 0..1
    const int n = (int)col0 + c;
    const int x = n / OC;
    const int o = o0 + (n - x * OC);
    const float bias = bias_xo[(((long long)z << 8) + x) * 128 + o];
    float* outp = Cf + z * sCz + (long long)x * (YY * LLn) + o;
    #pragma unroll
    for (int ch = 0; ch < 4; ch++) {
      #pragma unroll
      for (int tn = 0; tn < 4; tn++)
        #pragma unroll
        for (int e = 0; e < 4; e++)
          ebuf[((w >> 1) * 16 + fq * 4 + e) * 132 + wn + tn * 16 + fr] = acc[ch][tn][e];
      __syncthreads();
      const long long ybase = row0 + (long long)rgrp * 64 + ch * 16;
      #pragma unroll
      for (int r = 0; r < 16; r++)
        outp[(ybase + r) * LLn] = ebuf[(rgrp * 16 + r) * 132 + c] + bias;
      __syncthreads();
    }
  } else {
    const int er = fq * 4;
    #pragma unroll
    for (int tn = 0; tn < 4; tn++) {
      const long long col = col0 + wn + tn * 16 + fr;
      const float bv = cbias ? cbias[(long long)z * sbias + col] : 0.f;
      #pragma unroll
      for (int tm = 0; tm < 4; tm++) {
        const int rl = wm + tm * 16 + er;
        if (MODE == 0) {
          bf16_t* dst = Cb + z * sCz + col;
          #pragma unroll
          for (int r = 0; r < 4; r++)
            dst[(row0 + rl + r) * (long long)ldc] = (bf16_t)(acc[tm][tn][r] + bv);
        } else {
          float* dst = Cf + z * sCz + col;
          #pragma unroll
          for (int r = 0; r < 4; r++)
            dst[(row0 + rl + r) * (long long)ldc] = acc[tm][tn][r] + bv;
        }
      }
    }
  }
}

// ---------------- loss ----------------

__global__ void loss_kernel(const float* __restrict__ arc, const float* __restrict__ rel,
                            const int* __restrict__ la, const int* __restrict__ lr,
                            float* __restrict__ acc) {
  const int r = blockIdx.x;
  const int lane = threadIdx.x;    // 64
  const int lab = la[r];
  const float* ar = arc + (long long)r * YY;
  float v[8]; float m = -INFINITY;
  #pragma unroll
  for (int i = 0; i < 8; i++) { v[i] = ar[lane + 64 * i]; m = fmaxf(m, v[i]); }
  m = wave_max(m);
  float s = 0.f;
  #pragma unroll
  for (int i = 0; i < 8; i++) s += expf(v[i] - m);
  s = wave_sum(s);
  const float lse_a = m + logf(s);
  const int safe = lab < 0 ? 0 : (lab > YY - 1 ? YY - 1 : lab);
  const float* rr = rel + ((long long)r * YY + safe) * LLn;
  const float rv = (lane < LLn) ? rr[lane] : -INFINITY;
  const float m2 = wave_max(rv);
  const float s2 = wave_sum((lane < LLn) ? expf(rv - m2) : 0.f);
  const float lse_r = m2 + logf(s2);
  if (lane == 0 && lab != 0) {
    const float ll = (ar[safe] - lse_a) + (rr[lr[r]] - lse_r);
    atomicAdd(&acc[0], ll);
    atomicAdd(&acc[1], 1.f);
  }
}

__global__ void finalize(const float* __restrict__ acc, float* __restrict__ out) {
  out[0] = -acc[0] / acc[1];
}

// ---------------- launch ----------------

extern "C" void kernel_launch(void* const* d_in, const int* in_sizes, int n_in,
                              void* d_out, int out_size, void* d_ws, size_t ws_size,
                              hipStream_t stream) {
  (void)in_sizes; (void)n_in; (void)out_size;
  const float* hidden      = (const float*)d_in[0];
  const float* W_arc       = (const float*)d_in[1];
  const float* W_rel       = (const float*)d_in[2];
  const int* word_starts   = (const int*)d_in[3];
  const int* labels_arcs   = (const int*)d_in[4];
  const int* labels_rels   = (const int*)d_in[5];

  float* out = (float*)d_out;
  float* rel_out = out + 1;
  float* arc_out = rel_out + REL_ELEMS;

  char* ws = (char*)d_ws;
  float* lossacc  = (float*)ws;                                 // 2 floats (256B slot)
  bf16_t* yrb     = (bf16_t*)(ws + 256);                        // [16][512][768]
  bf16_t* Wab     = yrb + (size_t)NB * YY * HH;                 // [768][768]
  bf16_t* A1      = Wab + (size_t)HH * HH;                      // [4096][768]
  bf16_t* Wb768   = A1 + (size_t)NB * SS * HH;                  // [128][768]
  float*  biasArc = (float*)(Wb768 + (size_t)128 * HH);         // [768]
  float*  bias768b= biasArc + HH;                               // [128]
  float*  d_bias2 = bias768b + 128;                             // [4096][128] fp32
  float*  WbiasJ  = d_bias2 + (size_t)NB * SS * 128;            // [37][768] fp32
  bf16_t* Wbc     = (bf16_t*)(WbiasJ + (size_t)LLn * HH);       // [OC][768][768]

  const size_t fixedB = 256 +
      2 * ((size_t)NB * YY * HH + (size_t)HH * HH + (size_t)NB * SS * HH +
           (size_t)128 * HH) +
      4 * ((size_t)HH + 128 + (size_t)NB * SS * 128 + (size_t)LLn * HH);
  const size_t perOC = 2 * ((size_t)HH * HH + (size_t)NB * SS * HH);
  int OC = 1;
  if (ws_size > fixedB + perOC) {
    const size_t m = (ws_size - fixedB) / perOC;
    OC = (m > (size_t)LLn) ? LLn : (int)m;
  }
  bf16_t* M_p = Wbc + (size_t)OC * HH * HH;                     // [4096][OC][768]

  hid_rows<<<NB * SS, 192, 0, stream>>>(hidden, yrb);
  build_deps2<<<dim3(SS, NB), 256, 0, stream>>>(hidden, word_starts, yrb);
  conv_warc<<<dim3(24, 24), dim3(32, 8), 0, stream>>>(W_arc, Wab);
  build_misc<<<LLn + 1, 256, 0, stream>>>(W_rel, W_arc, WbiasJ, Wb768, bias768b, biasArc, lossacc);
  bias2_kernel<<<NB * SS, 256, 0, stream>>>(yrb, Wb768, bias768b, d_bias2);

  // A1 = deps @ W_arc[:768] + biasArc : [4096 x 768], K=768
  gemm_bt<0><<<dim3(6, 32, 1), 256, 0, stream>>>(
      yrb, 0, HH, 1, Wab, 0, HH, HH,
      nullptr, A1, 0, HH, biasArc, 0, 0, 0, nullptr);
  // arc_preds = A1 . heads^T, K=768
  gemm_bt<1><<<dim3(4, 2, NB), 256, 0, stream>>>(
      A1, (long long)SS * HH, HH, 0,
      yrb, (long long)YY * HH, HH, HH,
      arc_out, nullptr, (long long)SS * YY, YY, nullptr, 0, 0, 0, nullptr);

  for (int o0 = 0; o0 < LLn; o0 += OC) {
    const int oc = (LLn - o0 < OC) ? (LLn - o0) : OC;
    conv_wrel<<<dim3(24, 24, oc), dim3(32, 8), 0, stream>>>(W_rel, Wbc, o0);
    // M[b,x,o,j<768] = deps . Wbc[o]^T + WbiasJ[o], K=768
    gemm_bt<0><<<dim3(6, 32, oc), 256, 0, stream>>>(
        yrb, 0, HH, 1,
        Wbc, (long long)HH * HH, HH, HH,
        nullptr, M_p, HH, oc * HH, WbiasJ + (long long)o0 * HH, HH, 0, 0, nullptr);
    // rel[b,x,y,o] = yrb[b,y,:] . M[b,x,o,:] + bias2[b,x,o], K=768
    gemm_bt<2><<<dim3(2 * oc, 4, NB), 256, 0, stream>>>(
        yrb, (long long)YY * HH, HH, 0,
        M_p, (long long)SS * oc * HH, HH, HH,
        rel_out, nullptr, (long long)SS * YY * LLn, 0, nullptr, 0,
        oc, o0, d_bias2);
  }

  loss_kernel<<<NB * SS, 64, 0, stream>>>(arc_out, rel_out, labels_arcs, labels_rels, lossacc);
  finalize<<<1, 1, 0, stream>>>(lossacc, out);
}

// Round 3
// 962.082 us; speedup vs baseline: 1.2459x; 1.0383x over previous
//
#include <hip/hip_runtime.h>
#include <cmath>
#include <cstdint>

// B=16, S=256, H=768, L=37, Y=2S=512.
// d_out = [loss(1)] [rel_preds 16*256*512*37] [arc_preds 16*256*512]  (fp32)
//
// Pipeline (bf16 MFMA, fp32 accum). Ones-column factored out of all
// contractions (K=768 exactly), applied as fp32 epilogue biases:
//   yrb   = [hidden;deps]          bf16 [16][512][768]  (deps rows double as "xa")
//   A1    = deps @ W_arc[:768] + W_arc[768,:]
//   arc   = A1 @ heads^T
//   bias2 = deps . W_rel[o,:768,768] + W_rel[o,768,768]   (wave-dot kernel)
//   M     = deps @ W_rel[o,:768,:768]^T + W_rel[o,768,:]  [4096][oc][768] bf16
//   rel   = M . yrb + bias2        (LDS-restaged coalesced epilogue)
//
// GEMM: 128x128 tile, 4 waves, single-barrier double-buffered LDS.
// Grid is 1-D with chunked-bijective XCD swizzle (T1) + y-fastest decode:
// blocks sharing a B-panel (same col-tile, same z) land on ONE XCD so the
// panel is an L2 hit instead of an 8-way HBM refetch (measured: rel GEMM
// FETCH 460MB vs 233MB mandatory; M GEMM 305MB vs ~50MB).

#define NB 16
#define SS 256
#define HH 768
#define LLn 37
#define YY 512

static const long long REL_ELEMS = (long long)NB * SS * YY * LLn;

typedef __bf16 bf16_t;
typedef __bf16 bf16x8 __attribute__((ext_vector_type(8)));
typedef float f32x4 __attribute__((ext_vector_type(4)));

__device__ __forceinline__ void async_copy16(const void* g, void* l) {
  __builtin_amdgcn_global_load_lds((__attribute__((address_space(1))) void*)(g),
                                   (__attribute__((address_space(3))) void*)(l),
                                   16, 0, 0);
}

__device__ __forceinline__ float wave_max(float v) {
  #pragma unroll
  for (int off = 32; off > 0; off >>= 1) v = fmaxf(v, __shfl_xor(v, off));
  return v;
}
__device__ __forceinline__ float wave_sum(float v) {
  #pragma unroll
  for (int off = 32; off > 0; off >>= 1) v += __shfl_xor(v, off);
  return v;
}

// ---------------- prep kernels ----------------

__global__ void hid_rows(const float* __restrict__ hidden, bf16_t* __restrict__ yrb) {
  const long long r = blockIdx.x;            // b*256+y
  const int b = (int)(r >> 8), y = (int)(r & 255);
  const float4* src = (const float4*)(hidden + r * HH);
  bf16_t* dst = yrb + ((long long)b * YY + y) * HH;
  const int t = threadIdx.x;                 // 192 threads: 192*4 = 768
  const float4 v = src[t];
  bf16_t o4[4] = {(bf16_t)v.x, (bf16_t)v.y, (bf16_t)v.z, (bf16_t)v.w};
  *(ushort4*)(dst + t * 4) = *(ushort4*)o4;
}

// deps row x of batch b -> yrb[b][256+x][:768].  valid iff word_starts[x+1]!=0
__global__ void build_deps2(const float* __restrict__ hidden,
                            const int* __restrict__ word_starts,
                            bf16_t* __restrict__ yrb) {
  const int x = blockIdx.x, b = blockIdx.y, t = threadIdx.x;
  const int ws0 = word_starts[b * SS + x];
  const int ws1 = (x + 1 < SS) ? word_starts[b * SS + x + 1] : 0;
  const bool valid = (x + 1 < SS) && (ws1 != 0);
  const int start = min(max(ws0, 0), SS);
  const int end = min(max(ws1, 0), SS);
  const int len = max(end - start, 1);
  const float inv = 1.0f / (float)len;
  const float* hb = hidden + (long long)b * SS * HH;
  bf16_t* yr = yrb + ((long long)b * YY + SS + x) * HH;
  for (int h = t; h < HH; h += 256) {
    float s = 0.f;
    if (valid) for (int tt = start; tt < end; ++tt) s += hb[(long long)tt * HH + h];
    yr[h] = (bf16_t)(valid ? s * inv : 0.f);
  }
}

// W_arc [769,768] fp32 -> Wab [768][768] bf16 transposed (rows i<768 only)
__global__ void conv_warc(const float* __restrict__ W, bf16_t* __restrict__ Wab) {
  __shared__ float tbuf[32][33];
  const int i0 = blockIdx.x * 32, j0 = blockIdx.y * 32;
  const int tx = threadIdx.x, ty = threadIdx.y;   // 32x8
  for (int rr = 0; rr < 32; rr += 8)
    tbuf[ty + rr][tx] = W[(long long)(i0 + ty + rr) * HH + j0 + tx];
  __syncthreads();
  for (int rr = 0; rr < 32; rr += 8)
    Wab[(long long)(j0 + ty + rr) * HH + i0 + tx] = (bf16_t)tbuf[tx][ty + rr];
}

// W_rel [o][769][769] fp32 -> Wbc [z][768][768] bf16 transposed (i,j<768)
__global__ void conv_wrel(const float* __restrict__ W, bf16_t* __restrict__ Wb, int o0) {
  __shared__ float tbuf[32][33];
  const int o = o0 + blockIdx.z;
  const int i0 = blockIdx.x * 32, j0 = blockIdx.y * 32;
  const int tx = threadIdx.x, ty = threadIdx.y;   // 32x8
  const float* Wo = W + (long long)o * (HH + 1) * (HH + 1);
  for (int rr = 0; rr < 32; rr += 8)
    tbuf[ty + rr][tx] = Wo[(long long)(i0 + ty + rr) * (HH + 1) + j0 + tx];
  __syncthreads();
  bf16_t* Wbo = Wb + (long long)blockIdx.z * HH * HH;
  for (int rr = 0; rr < 32; rr += 8)
    Wbo[(long long)(j0 + ty + rr) * HH + i0 + tx] = (bf16_t)tbuf[tx][ty + rr];
}

// biases + the j=768 weight column:
//  WbiasJ[o][j] = W_rel[o][768][j]   (fp32, per-col bias of M)
//  Wb768[o][i]  = W_rel[o][i][768]   (bf16, weights of bias2 dot)
//  bias768b[o]  = W_rel[o][768][768] (fp32)
//  biasArc[j]   = W_arc[768][j]      (fp32);  lossacc zeroed
__global__ void build_misc(const float* __restrict__ W_rel, const float* __restrict__ W_arc,
                           float* __restrict__ WbiasJ, bf16_t* __restrict__ Wb768,
                           float* __restrict__ bias768b, float* __restrict__ biasArc,
                           float* __restrict__ lossacc) {
  const int blk = blockIdx.x, t = threadIdx.x;
  if (blk < LLn) {
    const int o = blk;
    const float* Wo = W_rel + (long long)o * (HH + 1) * (HH + 1);
    for (int j = t; j < HH; j += 256)
      WbiasJ[(long long)o * HH + j] = Wo[(long long)HH * (HH + 1) + j];
    for (int i = t; i < HH; i += 256)
      Wb768[(long long)o * HH + i] = (bf16_t)Wo[(long long)i * (HH + 1) + HH];
    if (t == 0) bias768b[o] = Wo[(long long)HH * (HH + 1) + HH];
  } else {
    for (int j = t; j < HH; j += 256) biasArc[j] = W_arc[(long long)HH * HH + j];
    if (t == 0) { lossacc[0] = 0.f; lossacc[1] = 0.f; }
  }
}

// bias2[r][o] = deps[r] . Wb768[o] + bias768b[o]   (r = b*256+x, o<37)
__global__ void bias2_kernel(const bf16_t* __restrict__ yrb,
                             const bf16_t* __restrict__ Wb768,
                             const float* __restrict__ bias768b,
                             float* __restrict__ d_bias2) {
  const int r = blockIdx.x;
  const int b = r >> 8, x = r & 255;
  const bf16_t* dep = yrb + ((long long)b * YY + SS + x) * HH;
  const int w = threadIdx.x >> 6, lane = threadIdx.x & 63;
  __shared__ float drow[HH];
  for (int h = threadIdx.x; h < HH; h += 256) drow[h] = (float)dep[h];
  __syncthreads();
  for (int o = w; o < LLn; o += 4) {
    const bf16_t* wrow = Wb768 + (long long)o * HH;
    float s = 0.f;
    #pragma unroll
    for (int i = 0; i < HH / 64; i++) s += drow[lane + 64 * i] * (float)wrow[lane + 64 * i];
    s = wave_sum(s);
    if (lane == 0) d_bias2[(long long)r * 128 + o] = s + bias768b[o];
  }
}

// ---------------- GEMM: C = A * B^T, 128x128 tile, bf16 MFMA 16x16x32 -------
// 1-D grid, chunked-bijective XCD swizzle, y-fastest decode (gy row-tiles,
// gx col-tiles, z = lid/(gy*gx)).  Single-barrier double-buffered LDS.
// aview!=0: A rows r=b*256+x map to yrb[b][256+x][:] (deps view).
// cbias (optional): per-column fp32 bias, cbias[z*sbias + col].
// MODE 0: bf16 out at Cb + z*sCz + row*ldc + col   (+cbias)
// MODE 1: fp32 out at Cf + z*sCz + row*ldc + col   (+cbias)
// MODE 2: rel out; col n -> (x=n/OC, o=o0+n%OC); LDS-restaged coalesced + bias_xo

template<int MODE>
__global__ __launch_bounds__(256)
void gemm_bt(const bf16_t* __restrict__ A, long long sAz, int lda, int aview,
             const bf16_t* __restrict__ B, long long sBz, int ldb,
             int K,
             float* __restrict__ Cf, bf16_t* __restrict__ Cb,
             long long sCz, int ldc,
             const float* __restrict__ cbias, int sbias,
             int OC, int o0, const float* __restrict__ bias_xo,
             int gy, int gx) {
  __shared__ __align__(16) char smem_raw[32768];   // 2 bufs x (A 8KB + B 8KB); ebuf 16896 fits
  bf16_t* const lds = (bf16_t*)smem_raw;           // buf c at c*8192 elems; B at +4096
  const int tid = threadIdx.x;
  const int w = tid >> 6;
  const int lane = tid & 63;

  // chunked-bijective XCD swizzle: hardware assigns block i -> XCD i%8;
  // give XCD k a contiguous logical chunk so same-B-panel blocks co-reside.
  const int nwg = (int)gridDim.x;
  const int q = nwg >> 3, r8 = nwg & 7;
  const int xcd = (int)blockIdx.x & 7, sub = (int)blockIdx.x >> 3;
  const int lid = ((xcd < r8) ? xcd * (q + 1) : r8 * (q + 1) + (xcd - r8) * q) + sub;
  const int yb = lid % gy;                          // row-tile fastest
  const int t2g = lid / gy;
  const int xb = t2g % gx;
  const int z = t2g / gx;

  const long long row0 = (long long)yb * 128;
  const long long col0 = (long long)xb * 128;
  const bf16_t* Ab;
  if (aview) {
    const long long bb = row0 >> 8;                // tile lies within one b
    Ab = A + (bb * 512 + 256 + (row0 & 255)) * (long long)lda;
  } else {
    Ab = A + z * sAz + row0 * lda;
  }
  const bf16_t* Bb = B + z * sBz + col0 * ldb;

  const int r_in = lane >> 2;
  const int kofs = (lane & 3) * 8;
  const bf16_t* gA0 = Ab + (long long)(w * 32 + r_in) * lda + kofs;
  const bf16_t* gA1 = gA0 + 16ll * lda;
  const bf16_t* gB0 = Bb + (long long)(w * 32 + r_in) * ldb + kofs;
  const bf16_t* gB1 = gB0 + 16ll * ldb;
  const int lA0 = (w * 32) * 32;
  const int lA1 = (w * 32 + 16) * 32;
  const int lB0 = 4096 + (w * 32) * 32;
  const int lB1 = 4096 + (w * 32 + 16) * 32;

  f32x4 acc[4][4];
  #pragma unroll
  for (int i = 0; i < 4; i++)
    #pragma unroll
    for (int j = 0; j < 4; j++)
      #pragma unroll
      for (int e = 0; e < 4; e++) acc[i][j][e] = 0.f;

  const int wm = (w >> 1) * 64, wn = (w & 1) * 64;
  const int fr = lane & 15;
  const int fq = lane >> 4;
  const int aoff = fq * 8;

  // prologue: stage tile 0 into buf 0
  async_copy16(gA0, lds + lA0);
  async_copy16(gA1, lds + lA1);
  async_copy16(gB0, lds + lB0);
  async_copy16(gB1, lds + lB1);
  __syncthreads();

  int cur = 0;
  for (int k0 = 32; k0 < K; k0 += 32) {
    bf16_t* nb = lds + (cur ^ 1) * 8192;
    async_copy16(gA0 + k0, nb + lA0);
    async_copy16(gA1 + k0, nb + lA1);
    async_copy16(gB0 + k0, nb + lB0);
    async_copy16(gB1 + k0, nb + lB1);
    const bf16_t* cb = lds + cur * 8192;
    bf16x8 af[4], bfr[4];
    #pragma unroll
    for (int t = 0; t < 4; t++) af[t]  = *(const bf16x8*)&cb[(wm + t * 16 + fr) * 32 + aoff];
    #pragma unroll
    for (int t = 0; t < 4; t++) bfr[t] = *(const bf16x8*)&cb[4096 + (wn + t * 16 + fr) * 32 + aoff];
    #pragma unroll
    for (int tm = 0; tm < 4; tm++)
      #pragma unroll
      for (int tn = 0; tn < 4; tn++)
        acc[tm][tn] = __builtin_amdgcn_mfma_f32_16x16x32_bf16(af[tm], bfr[tn], acc[tm][tn], 0, 0, 0);
    __syncthreads();   // drains stage (vmcnt 0) + all waves done with buf cur
    cur ^= 1;
  }
  {  // last tile (no prefetch)
    const bf16_t* cb = lds + cur * 8192;
    bf16x8 af[4], bfr[4];
    #pragma unroll
    for (int t = 0; t < 4; t++) af[t]  = *(const bf16x8*)&cb[(wm + t * 16 + fr) * 32 + aoff];
    #pragma unroll
    for (int t = 0; t < 4; t++) bfr[t] = *(const bf16x8*)&cb[4096 + (wn + t * 16 + fr) * 32 + aoff];
    #pragma unroll
    for (int tm = 0; tm < 4; tm++)
      #pragma unroll
      for (int tn = 0; tn < 4; tn++)
        acc[tm][tn] = __builtin_amdgcn_mfma_f32_16x16x32_bf16(af[tm], bfr[tn], acc[tm][tn], 0, 0, 0);
  }

  if (MODE == 2) {
    __syncthreads();                         // smem reuse: all reads done
    float* ebuf = (float*)smem_raw;          // [32][132]
    const int c = tid & 127;
    const int rgrp = tid >> 7;               // 0..1
    const int n = (int)col0 + c;
    const int x = n / OC;
    const int o = o0 + (n - x * OC);
    const float bias = bias_xo[(((long long)z << 8) + x) * 128 + o];
    float* outp = Cf + z * sCz + (long long)x * (YY * LLn) + o;
    #pragma unroll
    for (int ch = 0; ch < 4; ch++) {
      #pragma unroll
      for (int tn = 0; tn < 4; tn++)
        #pragma unroll
        for (int e = 0; e < 4; e++)
          ebuf[((w >> 1) * 16 + fq * 4 + e) * 132 + wn + tn * 16 + fr] = acc[ch][tn][e];
      __syncthreads();
      const long long ybase = row0 + (long long)rgrp * 64 + ch * 16;
      #pragma unroll
      for (int r = 0; r < 16; r++)
        outp[(ybase + r) * LLn] = ebuf[(rgrp * 16 + r) * 132 + c] + bias;
      __syncthreads();
    }
  } else {
    const int er = fq * 4;
    #pragma unroll
    for (int tn = 0; tn < 4; tn++) {
      const long long col = col0 + wn + tn * 16 + fr;
      const float bv = cbias ? cbias[(long long)z * sbias + col] : 0.f;
      #pragma unroll
      for (int tm = 0; tm < 4; tm++) {
        const int rl = wm + tm * 16 + er;
        if (MODE == 0) {
          bf16_t* dst = Cb + z * sCz + col;
          #pragma unroll
          for (int r = 0; r < 4; r++)
            dst[(row0 + rl + r) * (long long)ldc] = (bf16_t)(acc[tm][tn][r] + bv);
        } else {
          float* dst = Cf + z * sCz + col;
          #pragma unroll
          for (int r = 0; r < 4; r++)
            dst[(row0 + rl + r) * (long long)ldc] = acc[tm][tn][r] + bv;
        }
      }
    }
  }
}

// ---------------- loss ----------------

__global__ void loss_kernel(const float* __restrict__ arc, const float* __restrict__ rel,
                            const int* __restrict__ la, const int* __restrict__ lr,
                            float* __restrict__ acc) {
  const int r = blockIdx.x;
  const int lane = threadIdx.x;    // 64
  const int lab = la[r];
  const float* ar = arc + (long long)r * YY;
  float v[8]; float m = -INFINITY;
  #pragma unroll
  for (int i = 0; i < 8; i++) { v[i] = ar[lane + 64 * i]; m = fmaxf(m, v[i]); }
  m = wave_max(m);
  float s = 0.f;
  #pragma unroll
  for (int i = 0; i < 8; i++) s += expf(v[i] - m);
  s = wave_sum(s);
  const float lse_a = m + logf(s);
  const int safe = lab < 0 ? 0 : (lab > YY - 1 ? YY - 1 : lab);
  const float* rr = rel + ((long long)r * YY + safe) * LLn;
  const float rv = (lane < LLn) ? rr[lane] : -INFINITY;
  const float m2 = wave_max(rv);
  const float s2 = wave_sum((lane < LLn) ? expf(rv - m2) : 0.f);
  const float lse_r = m2 + logf(s2);
  if (lane == 0 && lab != 0) {
    const float ll = (ar[safe] - lse_a) + (rr[lr[r]] - lse_r);
    atomicAdd(&acc[0], ll);
    atomicAdd(&acc[1], 1.f);
  }
}

__global__ void finalize(const float* __restrict__ acc, float* __restrict__ out) {
  out[0] = -acc[0] / acc[1];
}

// ---------------- launch ----------------

extern "C" void kernel_launch(void* const* d_in, const int* in_sizes, int n_in,
                              void* d_out, int out_size, void* d_ws, size_t ws_size,
                              hipStream_t stream) {
  (void)in_sizes; (void)n_in; (void)out_size;
  const float* hidden      = (const float*)d_in[0];
  const float* W_arc       = (const float*)d_in[1];
  const float* W_rel       = (const float*)d_in[2];
  const int* word_starts   = (const int*)d_in[3];
  const int* labels_arcs   = (const int*)d_in[4];
  const int* labels_rels   = (const int*)d_in[5];

  float* out = (float*)d_out;
  float* rel_out = out + 1;
  float* arc_out = rel_out + REL_ELEMS;

  char* ws = (char*)d_ws;
  float* lossacc  = (float*)ws;                                 // 2 floats (256B slot)
  bf16_t* yrb     = (bf16_t*)(ws + 256);                        // [16][512][768]
  bf16_t* Wab     = yrb + (size_t)NB * YY * HH;                 // [768][768]
  bf16_t* A1      = Wab + (size_t)HH * HH;                      // [4096][768]
  bf16_t* Wb768   = A1 + (size_t)NB * SS * HH;                  // [128][768]
  float*  biasArc = (float*)(Wb768 + (size_t)128 * HH);         // [768]
  float*  bias768b= biasArc + HH;                               // [128]
  float*  d_bias2 = bias768b + 128;                             // [4096][128] fp32
  float*  WbiasJ  = d_bias2 + (size_t)NB * SS * 128;            // [37][768] fp32
  bf16_t* Wbc     = (bf16_t*)(WbiasJ + (size_t)LLn * HH);       // [OC][768][768]

  const size_t fixedB = 256 +
      2 * ((size_t)NB * YY * HH + (size_t)HH * HH + (size_t)NB * SS * HH +
           (size_t)128 * HH) +
      4 * ((size_t)HH + 128 + (size_t)NB * SS * 128 + (size_t)LLn * HH);
  const size_t perOC = 2 * ((size_t)HH * HH + (size_t)NB * SS * HH);
  int OC = 1;
  if (ws_size > fixedB + perOC) {
    const size_t m = (ws_size - fixedB) / perOC;
    OC = (m > (size_t)LLn) ? LLn : (int)m;
  }
  bf16_t* M_p = Wbc + (size_t)OC * HH * HH;                     // [4096][OC][768]

  hid_rows<<<NB * SS, 192, 0, stream>>>(hidden, yrb);
  build_deps2<<<dim3(SS, NB), 256, 0, stream>>>(hidden, word_starts, yrb);
  conv_warc<<<dim3(24, 24), dim3(32, 8), 0, stream>>>(W_arc, Wab);
  build_misc<<<LLn + 1, 256, 0, stream>>>(W_rel, W_arc, WbiasJ, Wb768, bias768b, biasArc, lossacc);
  bias2_kernel<<<NB * SS, 256, 0, stream>>>(yrb, Wb768, bias768b, d_bias2);

  // A1 = deps @ W_arc[:768] + biasArc : [4096 x 768], K=768  (gy=32, gx=6)
  gemm_bt<0><<<192, 256, 0, stream>>>(
      yrb, 0, HH, 1, Wab, 0, HH, HH,
      nullptr, A1, 0, HH, biasArc, 0, 0, 0, nullptr, 32, 6);
  // arc_preds = A1 . heads^T, K=768  (gy=2, gx=4, gz=16)
  gemm_bt<1><<<128, 256, 0, stream>>>(
      A1, (long long)SS * HH, HH, 0,
      yrb, (long long)YY * HH, HH, HH,
      arc_out, nullptr, (long long)SS * YY, YY, nullptr, 0, 0, 0, nullptr, 2, 4);

  for (int o0 = 0; o0 < LLn; o0 += OC) {
    const int oc = (LLn - o0 < OC) ? (LLn - o0) : OC;
    conv_wrel<<<dim3(24, 24, oc), dim3(32, 8), 0, stream>>>(W_rel, Wbc, o0);
    // M[b,x,o,j<768] = deps . Wbc[o]^T + WbiasJ[o], K=768  (gy=32, gx=6, gz=oc)
    gemm_bt<0><<<192 * oc, 256, 0, stream>>>(
        yrb, 0, HH, 1,
        Wbc, (long long)HH * HH, HH, HH,
        nullptr, M_p, HH, oc * HH, WbiasJ + (long long)o0 * HH, HH, 0, 0, nullptr, 32, 6);
    // rel[b,x,y,o] = yrb[b,y,:] . M[b,x,o,:] + bias2[b,x,o], K=768  (gy=4, gx=2oc, gz=16)
    gemm_bt<2><<<128 * oc, 256, 0, stream>>>(
        yrb, (long long)YY * HH, HH, 0,
        M_p, (long long)SS * oc * HH, HH, HH,
        rel_out, nullptr, (long long)SS * YY * LLn, 0, nullptr, 0,
        oc, o0, d_bias2, 4, 2 * oc);
  }

  loss_kernel<<<NB * SS, 64, 0, stream>>>(arc_out, rel_out, labels_arcs, labels_rels, lossacc);
  finalize<<<1, 1, 0, stream>>>(lossacc, out);
}